// Round 2
// baseline (7073.533 us; speedup 1.0000x reference)
//
#include <hip/hip_runtime.h>
#include <math.h>

#define Bsz 8
#define Cdim 512
#define Tdim 4096
#define NHq 8
#define CD 96
#define NB 8
#define NE 1024
#define NCHq 256
#define Mtok (Bsz*Tdim)     // 32768
#define M2tok (Bsz*NCHq)    // 2048

// ---------------- pe + constant query rows ----------------
__global__ __launch_bounds__(256) void pe_qc_kernel(float* pe_tab, float* qc_ln,
        const float* __restrict__ lnq_g, const float* __restrict__ lnq_b){
  int t = blockIdx.x;           // 0..15
  int tid = threadIdx.x;
  __shared__ float red[256];
  double f = -log(10000.0) / (double)Cdim;
  float v[2];
  #pragma unroll
  for (int u = 0; u < 2; ++u){
    int c = tid + u*256;
    int ce = c & ~1;
    double ang = (double)t * exp(f * (double)ce);
    v[u] = (float)((c & 1) ? cos(ang) : sin(ang));
    pe_tab[t*Cdim + c] = v[u];
  }
  red[tid] = v[0] + v[1]; __syncthreads();
  for (int s = 128; s > 0; s >>= 1){ if (tid < s) red[tid] += red[tid+s]; __syncthreads(); }
  float mean = red[0] * (1.f/512.f); __syncthreads();
  float d0 = v[0]-mean, d1 = v[1]-mean;
  red[tid] = d0*d0 + d1*d1; __syncthreads();
  for (int s = 128; s > 0; s >>= 1){ if (tid < s) red[tid] += red[tid+s]; __syncthreads(); }
  float rstd = 1.0f/sqrtf(red[0]*(1.f/512.f) + 1e-5f);
  qc_ln[t*Cdim + tid]       = d0*rstd*lnq_g[tid]     + lnq_b[tid];
  qc_ln[t*Cdim + tid + 256] = d1*rstd*lnq_g[tid+256] + lnq_b[tid+256];
}

// ---------------- generic row LayerNorm (rows of 512) ----------------
// mode 0: dst = norm*g+b ; mode 1: dst = tanh(norm*g+b)*clip(scale)
__global__ __launch_bounds__(256) void ln_rows_kernel(const float* __restrict__ src, float* __restrict__ dst,
        const float* __restrict__ g, const float* __restrict__ bia, int mode, const float* __restrict__ scale_ptr){
  int row = blockIdx.x; int tid = threadIdx.x;
  const float* sr = src + (size_t)row*Cdim;
  float v0 = sr[tid], v1 = sr[tid+256];
  __shared__ float red[256];
  red[tid] = v0+v1; __syncthreads();
  for (int s = 128; s > 0; s >>= 1){ if (tid < s) red[tid] += red[tid+s]; __syncthreads(); }
  float mean = red[0]*(1.f/512.f); __syncthreads();
  float d0 = v0-mean, d1 = v1-mean;
  red[tid] = d0*d0 + d1*d1; __syncthreads();
  for (int s = 128; s > 0; s >>= 1){ if (tid < s) red[tid] += red[tid+s]; __syncthreads(); }
  float rstd = 1.0f/sqrtf(red[0]*(1.f/512.f) + 1e-5f);
  float h0 = d0*rstd*g[tid]     + bia[tid];
  float h1 = d1*rstd*g[tid+256] + bia[tid+256];
  if (mode == 1){
    float sc = *scale_ptr; sc = fminf(fmaxf(sc, 0.005f), 0.5f);
    h0 = tanhf(h0)*sc; h1 = tanhf(h1)*sc;
  }
  float* dr = dst + (size_t)row*Cdim;
  dr[tid] = h0; dr[tid+256] = h1;
}

// ---------------- transposes [B,C,T] <-> token rows [B*T, C] ----------------
__global__ void tin_kernel(const float* __restrict__ qa, const float* __restrict__ pe_tab, float* __restrict__ rows){
  __shared__ float tile[32][33];
  int b = blockIdx.z, c0 = blockIdx.y*32, t0 = blockIdx.x*32;
  int tx = threadIdx.x, ty = threadIdx.y;
  int t = t0 + tx;
  #pragma unroll
  for (int j = 0; j < 4; j++){
    int c = c0 + ty + j*8;
    tile[ty+j*8][tx] = qa[((size_t)(b*Cdim + c))*Tdim + t] + pe_tab[(t & 15)*Cdim + c];
  }
  __syncthreads();
  #pragma unroll
  for (int j = 0; j < 4; j++){
    int tt = t0 + ty + j*8;
    rows[((size_t)(b*Tdim + tt))*Cdim + c0 + tx] = tile[tx][ty+j*8];
  }
}

__global__ void resid_kernel(const float* __restrict__ zt, const float* __restrict__ zp_rows, float* __restrict__ rows){
  __shared__ float tile[32][33];
  int b = blockIdx.z, c0 = blockIdx.y*32, t0 = blockIdx.x*32;
  int tx = threadIdx.x, ty = threadIdx.y;
  int t = t0 + tx;
  #pragma unroll
  for (int j = 0; j < 4; j++){
    int c = c0 + ty + j*8;
    tile[ty+j*8][tx] = zt[((size_t)(b*Cdim + c))*Tdim + t];
  }
  __syncthreads();
  #pragma unroll
  for (int j = 0; j < 4; j++){
    int tt = t0 + ty + j*8;
    size_t o = ((size_t)(b*Tdim + tt))*Cdim + c0 + tx;
    rows[o] = tile[tx][ty+j*8] - zp_rows[o];
  }
}

__global__ void tout_kernel(const float* __restrict__ rows, float* __restrict__ out){
  __shared__ float tile[32][33];
  int b = blockIdx.z, c0 = blockIdx.y*32, t0 = blockIdx.x*32;
  int tx = threadIdx.x, ty = threadIdx.y;
  #pragma unroll
  for (int j = 0; j < 4; j++){
    int tt = t0 + ty + j*8;
    tile[ty+j*8][tx] = rows[((size_t)(b*Tdim + tt))*Cdim + c0 + tx];
  }
  __syncthreads();
  #pragma unroll
  for (int j = 0; j < 4; j++){
    int c = c0 + ty + j*8;
    out[((size_t)(b*Cdim + c))*Tdim + t0 + tx] = tile[tx][ty+j*8];
  }
}

// ---------------- weight transposes ----------------
__global__ void twd_kernel(const float* __restrict__ Wd, float* __restrict__ WdT){ // Wd[96][512] -> WdT[512][96]
  int i = blockIdx.x*256 + threadIdx.x; if (i >= 96*512) return;
  int kq = i / 96, n = i % 96;
  WdT[i] = Wd[(size_t)n*512 + kq];
}
__global__ void twu_kernel(const float* __restrict__ Wu, float* __restrict__ WuT){ // Wu[512][96] -> WuT[96][512]
  int i = blockIdx.x*256 + threadIdx.x; if (i >= 96*512) return;
  int d = i / 512, c = i % 512;
  WuT[i] = Wu[(size_t)c*96 + d];
}

// ---------------- 0.5*||e||^2 per codebook entry ----------------
__global__ void hb_kernel(const float* __restrict__ books, float* __restrict__ hb){
  int j = blockIdx.x*256 + threadIdx.x;
  if (j >= NB*NE) return;
  const float* e = books + (size_t)j*CD;
  float s = 0.f;
  #pragma unroll
  for (int d = 0; d < CD; d++) s = fmaf(e[d], e[d], s);
  hb[j] = 0.5f*s;
}

// ---------------- generic tiled fp32 GEMM: C = act(A@B + bias) + add ----------------
// addmode: 0 none, 1 addbuf[(m&15)*N+n] (constant query rows), 2 addbuf[m*N+n]
__global__ __launch_bounds__(256) void gemm_kernel(const float* __restrict__ A, const float* __restrict__ Bm,
        float* __restrict__ Cm, int M, int N, int K,
        const float* __restrict__ bias, const float* __restrict__ addbuf, int addmode, int act){
  __shared__ float As[16][65];
  __shared__ float Bs[16][64];
  int l = threadIdx.x;
  int tx = l & 15, ty = l >> 4;
  int m0 = blockIdx.y*64, n0 = blockIdx.x*64;
  int ai = l >> 2, ak = (l & 3)*4;
  int bk = l >> 4, bj = (l & 15)*4;
  float acc[4][4] = {{0.f}};
  bool nfull = (n0 + 64 <= N);
  for (int k0 = 0; k0 < K; k0 += 16){
    float4 av = make_float4(0.f, 0.f, 0.f, 0.f);
    if (m0 + ai < M) av = *(const float4*)(A + (size_t)(m0+ai)*K + k0 + ak);
    As[ak][ai] = av.x; As[ak+1][ai] = av.y; As[ak+2][ai] = av.z; As[ak+3][ai] = av.w;
    if (nfull){
      *(float4*)(&Bs[bk][bj]) = *(const float4*)(Bm + (size_t)(k0+bk)*N + n0 + bj);
    } else {
      #pragma unroll
      for (int u = 0; u < 4; u++){
        int n = n0 + bj + u;
        Bs[bk][bj+u] = (n < N) ? Bm[(size_t)(k0+bk)*N + n] : 0.f;
      }
    }
    __syncthreads();
    #pragma unroll
    for (int kk = 0; kk < 16; kk++){
      float a0 = As[kk][ty*4], a1 = As[kk][ty*4+1], a2 = As[kk][ty*4+2], a3 = As[kk][ty*4+3];
      float b0 = Bs[kk][tx*4], b1 = Bs[kk][tx*4+1], b2 = Bs[kk][tx*4+2], b3 = Bs[kk][tx*4+3];
      acc[0][0] = fmaf(a0,b0,acc[0][0]); acc[0][1] = fmaf(a0,b1,acc[0][1]);
      acc[0][2] = fmaf(a0,b2,acc[0][2]); acc[0][3] = fmaf(a0,b3,acc[0][3]);
      acc[1][0] = fmaf(a1,b0,acc[1][0]); acc[1][1] = fmaf(a1,b1,acc[1][1]);
      acc[1][2] = fmaf(a1,b2,acc[1][2]); acc[1][3] = fmaf(a1,b3,acc[1][3]);
      acc[2][0] = fmaf(a2,b0,acc[2][0]); acc[2][1] = fmaf(a2,b1,acc[2][1]);
      acc[2][2] = fmaf(a2,b2,acc[2][2]); acc[2][3] = fmaf(a2,b3,acc[2][3]);
      acc[3][0] = fmaf(a3,b0,acc[3][0]); acc[3][1] = fmaf(a3,b1,acc[3][1]);
      acc[3][2] = fmaf(a3,b2,acc[3][2]); acc[3][3] = fmaf(a3,b3,acc[3][3]);
    }
    __syncthreads();
  }
  #pragma unroll
  for (int r = 0; r < 4; r++){
    int m = m0 + ty*4 + r; if (m >= M) continue;
    #pragma unroll
    for (int c = 0; c < 4; c++){
      int n = n0 + tx*4 + c; if (n >= N) continue;
      float v = acc[r][c];
      if (bias) v += bias[n];
      if (act == 1) v = 0.5f*v*(1.0f + erff(v*0.7071067811865475f));
      if (addmode == 1) v += addbuf[(size_t)(m & 15)*N + n];
      else if (addmode == 2) v += addbuf[(size_t)m*N + n];
      Cm[(size_t)m*N + n] = v;
    }
  }
}

// ---------------- attention, phase 1: 16 const queries x 16 keys per (b,chunk) ----------------
__global__ __launch_bounds__(128) void attn1_kernel(const float* __restrict__ Kb, const float* __restrict__ Vb,
        const float* __restrict__ Qp, float* __restrict__ ctxb){
  int idx = blockIdx.x;                 // b*256 + ch
  int b = idx >> 8, ch = idx & 255;
  size_t m0 = (size_t)b*Tdim + ch*16;
  int t = threadIdx.x >> 3, h = threadIdx.x & 7;
  const float* q = Qp + t*Cdim + h*64;
  float qr[64];
  #pragma unroll
  for (int d = 0; d < 64; d += 4){ float4 f = *(const float4*)(q+d); qr[d]=f.x; qr[d+1]=f.y; qr[d+2]=f.z; qr[d+3]=f.w; }
  float s[16];
  #pragma unroll
  for (int k = 0; k < 16; k++){
    const float* kr = Kb + (m0+k)*Cdim + h*64;
    float acc = 0.f;
    #pragma unroll
    for (int d = 0; d < 64; d += 4){
      float4 f = *(const float4*)(kr+d);
      acc = fmaf(qr[d],f.x,acc); acc = fmaf(qr[d+1],f.y,acc);
      acc = fmaf(qr[d+2],f.z,acc); acc = fmaf(qr[d+3],f.w,acc);
    }
    s[k] = acc * 0.125f;
  }
  float mx = s[0];
  #pragma unroll
  for (int k = 1; k < 16; k++) mx = fmaxf(mx, s[k]);
  float sum = 0.f;
  #pragma unroll
  for (int k = 0; k < 16; k++){ s[k] = expf(s[k]-mx); sum += s[k]; }
  float inv = 1.0f/sum;
  float ctx[64];
  #pragma unroll
  for (int d = 0; d < 64; d++) ctx[d] = 0.f;
  #pragma unroll
  for (int k = 0; k < 16; k++){
    float p = s[k]*inv;
    const float* vr = Vb + (m0+k)*Cdim + h*64;
    #pragma unroll
    for (int d = 0; d < 64; d += 4){
      float4 f = *(const float4*)(vr+d);
      ctx[d]=fmaf(p,f.x,ctx[d]); ctx[d+1]=fmaf(p,f.y,ctx[d+1]);
      ctx[d+2]=fmaf(p,f.z,ctx[d+2]); ctx[d+3]=fmaf(p,f.w,ctx[d+3]);
    }
  }
  float* o = ctxb + (m0+t)*Cdim + h*64;
  #pragma unroll
  for (int d = 0; d < 64; d += 4){
    float4 f; f.x=ctx[d]; f.y=ctx[d+1]; f.z=ctx[d+2]; f.w=ctx[d+3];
    *(float4*)(o+d) = f;
  }
}

// ---------------- attention, phase 2: 1 query (token 0) per (b,chunk) ----------------
__global__ __launch_bounds__(64) void attn2_kernel(const float* __restrict__ Kb, const float* __restrict__ Vb,
        const float* __restrict__ Qp, float* __restrict__ ctxb){
  int m2 = blockIdx.x;                 // b*256 + ch
  int b = m2 >> 8, ch = m2 & 255;
  size_t m0 = (size_t)b*Tdim + ch*16;
  int h = threadIdx.x;
  if (h >= 8) return;
  const float* q = Qp + (size_t)m2*Cdim + h*64;
  float qr[64];
  #pragma unroll
  for (int d = 0; d < 64; d += 4){ float4 f = *(const float4*)(q+d); qr[d]=f.x; qr[d+1]=f.y; qr[d+2]=f.z; qr[d+3]=f.w; }
  float s[16];
  #pragma unroll
  for (int k = 0; k < 16; k++){
    const float* kr = Kb + (m0+k)*Cdim + h*64;
    float acc = 0.f;
    #pragma unroll
    for (int d = 0; d < 64; d += 4){
      float4 f = *(const float4*)(kr+d);
      acc = fmaf(qr[d],f.x,acc); acc = fmaf(qr[d+1],f.y,acc);
      acc = fmaf(qr[d+2],f.z,acc); acc = fmaf(qr[d+3],f.w,acc);
    }
    s[k] = acc * 0.125f;
  }
  float mx = s[0];
  #pragma unroll
  for (int k = 1; k < 16; k++) mx = fmaxf(mx, s[k]);
  float sum = 0.f;
  #pragma unroll
  for (int k = 0; k < 16; k++){ s[k] = expf(s[k]-mx); sum += s[k]; }
  float inv = 1.0f/sum;
  float ctx[64];
  #pragma unroll
  for (int d = 0; d < 64; d++) ctx[d] = 0.f;
  #pragma unroll
  for (int k = 0; k < 16; k++){
    float p = s[k]*inv;
    const float* vr = Vb + (m0+k)*Cdim + h*64;
    #pragma unroll
    for (int d = 0; d < 64; d += 4){
      float4 f = *(const float4*)(vr+d);
      ctx[d]=fmaf(p,f.x,ctx[d]); ctx[d+1]=fmaf(p,f.y,ctx[d+1]);
      ctx[d+2]=fmaf(p,f.z,ctx[d+2]); ctx[d+3]=fmaf(p,f.w,ctx[d+3]);
    }
  }
  float* o = ctxb + (size_t)m2*Cdim + h*64;
  #pragma unroll
  for (int d = 0; d < 64; d += 4){
    float4 f; f.x=ctx[d]; f.y=ctx[d+1]; f.z=ctx[d+2]; f.w=ctx[d+3];
    *(float4*)(o+d) = f;
  }
}

// ---------------- phase 2: build token-0 query rows (carry + pe[:,0], LN) ----------------
__global__ __launch_bounds__(256) void q2_kernel(const float* __restrict__ dout, float* __restrict__ p2q,
        const float* __restrict__ g, const float* __restrict__ bia){
  int m2 = blockIdx.x; int tid = threadIdx.x;
  int b = m2 >> 8, ch = m2 & 255;
  int tprev = ch*16 - 1;
  float v0, v1;
  {
    int c = tid;
    float carry = (ch == 0) ? 0.f : dout[((size_t)(b*Cdim + c))*Tdim + tprev];
    v0 = carry + ((c & 1) ? 1.f : 0.f);     // pe[c,0] = c even ? sin(0)=0 : cos(0)=1
  }
  {
    int c = tid + 256;
    float carry = (ch == 0) ? 0.f : dout[((size_t)(b*Cdim + c))*Tdim + tprev];
    v1 = carry + ((c & 1) ? 1.f : 0.f);
  }
  __shared__ float red[256];
  red[tid] = v0+v1; __syncthreads();
  for (int s = 128; s > 0; s >>= 1){ if (tid < s) red[tid] += red[tid+s]; __syncthreads(); }
  float mean = red[0]*(1.f/512.f); __syncthreads();
  float d0 = v0-mean, d1 = v1-mean;
  red[tid] = d0*d0 + d1*d1; __syncthreads();
  for (int s = 128; s > 0; s >>= 1){ if (tid < s) red[tid] += red[tid+s]; __syncthreads(); }
  float rstd = 1.0f/sqrtf(red[0]*(1.f/512.f) + 1e-5f);
  p2q[(size_t)m2*Cdim + tid]       = d0*rstd*g[tid]     + bia[tid];
  p2q[(size_t)m2*Cdim + tid + 256] = d1*rstd*g[tid+256] + bia[tid+256];
}

// ---------------- phase 2: r = zt[:, :, t0] - z_pred0 ----------------
__global__ __launch_bounds__(256) void r2_kernel(const float* __restrict__ zt, const float* __restrict__ zp,
        float* __restrict__ out){
  int m2 = blockIdx.x; int tid = threadIdx.x;
  int b = m2 >> 8, ch = m2 & 255; int t0 = ch*16;
  #pragma unroll
  for (int u = 0; u < 2; u++){
    int c = tid + u*256;
    out[(size_t)m2*Cdim + c] = zt[((size_t)(b*Cdim + c))*Tdim + t0] - zp[(size_t)m2*Cdim + c];
  }
}

// ---------------- phase 2: scatter z_hat token-0 columns into d_out ----------------
__global__ __launch_bounds__(256) void scatter2_kernel(const float* __restrict__ z, float* __restrict__ dout){
  int m2 = blockIdx.x; int tid = threadIdx.x;
  int b = m2 >> 8, ch = m2 & 255; int t0 = ch*16;
  #pragma unroll
  for (int u = 0; u < 2; u++){
    int c = tid + u*256;
    dout[((size_t)(b*Cdim + c))*Tdim + t0] = z[(size_t)m2*Cdim + c];
  }
}

// ---------------- residual VQ: 8 codebooks, straight-through == q_sum = x - residual_8 ----------------
// block = 256 threads = 4 waves; 64 tokens/block; wave w scans candidates [w*256, w*256+256)
__global__ __launch_bounds__(256) void vq_kernel(float* __restrict__ x, const float* __restrict__ books,
        const float* __restrict__ hb){
  int lane = threadIdx.x & 63;
  int wv = threadIdx.x >> 6;
  size_t tok = (size_t)blockIdx.x*64 + lane;
  float res[96];
  #pragma unroll
  for (int d = 0; d < 96; d += 4){
    float4 f = *(const float4*)(x + tok*CD + d);
    res[d]=f.x; res[d+1]=f.y; res[d+2]=f.z; res[d+3]=f.w;
  }
  __shared__ float s_best[4][64];
  __shared__ int   s_idx[4][64];
  __shared__ int   s_sel[64];
  for (int k = 0; k < NB; k++){
    const float* bk = books + (size_t)k*NE*CD;
    const float* hk = hb + k*NE;
    float best = -3.0e38f; int bidx = 0;
    int cbase = __builtin_amdgcn_readfirstlane(wv*256);
    for (int cc = 0; cc < 256; cc += 2){
      int c0 = cbase + cc;
      const float* e0 = bk + (size_t)c0*CD;
      float a0 = -hk[c0], a1 = -hk[c0+1];
      #pragma unroll
      for (int d = 0; d < 96; d++){
        a0 = fmaf(res[d], e0[d],    a0);
        a1 = fmaf(res[d], e0[96+d], a1);
      }
      if (a0 > best){ best = a0; bidx = c0; }
      if (a1 > best){ best = a1; bidx = c0 + 1; }
    }
    s_best[wv][lane] = best; s_idx[wv][lane] = bidx;
    __syncthreads();
    if (wv == 0){
      float bb = s_best[0][lane]; int bi = s_idx[0][lane];
      #pragma unroll
      for (int w = 1; w < 4; w++){
        float b2 = s_best[w][lane]; int i2 = s_idx[w][lane];
        if (b2 > bb){ bb = b2; bi = i2; }      // ranges ascending -> first-max tie rule
      }
      s_sel[lane] = bi;
    }
    __syncthreads();
    int sel = s_sel[lane];
    const float* ev = bk + (size_t)sel*CD;
    #pragma unroll
    for (int d = 0; d < 96; d += 4){
      float4 f = *(const float4*)(ev + d);
      res[d]-=f.x; res[d+1]-=f.y; res[d+2]-=f.z; res[d+3]-=f.w;
    }
    __syncthreads();
  }
  if (wv == 0){
    #pragma unroll
    for (int d = 0; d < 96; d += 4){
      float4 xo = *(const float4*)(x + tok*CD + d);
      float4 q;
      q.x = xo.x - res[d]; q.y = xo.y - res[d+1]; q.z = xo.z - res[d+2]; q.w = xo.w - res[d+3];
      *(float4*)(x + tok*CD + d) = q;
    }
  }
}

// ---------------- host ----------------
extern "C" void kernel_launch(void* const* d_in, const int* in_sizes, int n_in,
                              void* d_out, int out_size, void* d_ws, size_t ws_size,
                              hipStream_t stream) {
  const float* qa    = (const float*)d_in[0];
  const float* zt    = (const float*)d_in[1];
  const float* lnq_g = (const float*)d_in[2];
  const float* lnq_b = (const float*)d_in[3];
  const float* lnkv_g= (const float*)d_in[4];
  const float* lnkv_b= (const float*)d_in[5];
  const float* Wq    = (const float*)d_in[6];
  const float* Wk    = (const float*)d_in[7];
  const float* Wv    = (const float*)d_in[8];
  const float* Wo    = (const float*)d_in[9];
  const float* ffn_g = (const float*)d_in[10];
  const float* ffn_b = (const float*)d_in[11];
  const float* W1    = (const float*)d_in[12];
  const float* b1    = (const float*)d_in[13];
  const float* W2    = (const float*)d_in[14];
  const float* b2    = (const float*)d_in[15];
  const float* tn_g  = (const float*)d_in[16];
  const float* tn_b  = (const float*)d_in[17];
  const float* scale = (const float*)d_in[18];
  const float* Wd    = (const float*)d_in[19];
  const float* bd    = (const float*)d_in[20];
  const float* Wu    = (const float*)d_in[21];
  const float* bu    = (const float*)d_in[22];
  const float* books = (const float*)d_in[23];
  float* out = (float*)d_out;

  // ---- workspace layout (total ~208.5 MiB) ----
  float* ws = (float*)d_ws;
  size_t off = 0;
  float* pe_tab  = ws + off; off += 16*512;
  float* qc_ln   = ws + off; off += 16*512;
  float* qc_proj = ws + off; off += 16*512;
  float* WdT     = ws + off; off += 512*96;
  float* WuT     = ws + off; off += 96*512;
  float* hbuf    = ws + off; off += 8*1024;
  float* bA      = ws + off; off += (size_t)Mtok*512;   // kv rows -> ctx -> lny -> rn -> zhat rows -> phase2 scratch
  float* bK      = ws + off; off += (size_t)Mtok*512;
  float* bV      = ws + off; off += (size_t)Mtok*512;
  float* bH      = ws + off; off += (size_t)4096*1024;  // FFN hidden tile; also hosts bX
  float* bX      = bH;                                  // Mtok*96 = 12.6MB <= 16.8MB, used after FFN done
  // y / z_pred rows [Mtok,512] live in d_out (same element count); dead before tout overwrites d_out
  float* bY      = out;

  // phase-2 scratch carved inside bA (only used after tout consumes bA)
  float* p2q   = bA;
  float* p2Qp  = bA + 1048576;
  float* p2ctx = bA + 2*1048576;
  float* p2y   = bA + 3*1048576;
  float* p2lny = bA + 4*1048576;
  float* p2h   = bA + 5*1048576;          // 2048*1024
  float* p2r   = bA + 7*1048576;
  float* p2x   = bA + 8*1048576;          // 2048*96
  float* p2z   = bA + 8*1048576 + 196608;

  dim3 tpb32(32, 8);
  dim3 tgrid(Tdim/32, Cdim/32, Bsz);

  // ---- prep ----
  hipLaunchKernelGGL(pe_qc_kernel, dim3(16), dim3(256), 0, stream, pe_tab, qc_ln, lnq_g, lnq_b);
  hipLaunchKernelGGL(twd_kernel, dim3((96*512+255)/256), dim3(256), 0, stream, Wd, WdT);
  hipLaunchKernelGGL(twu_kernel, dim3((96*512+255)/256), dim3(256), 0, stream, Wu, WuT);
  hipLaunchKernelGGL(hb_kernel, dim3((NB*NE+255)/256), dim3(256), 0, stream, books, hbuf);

  // ---- phase 1: kv path ----
  hipLaunchKernelGGL(tin_kernel, tgrid, tpb32, 0, stream, qa, pe_tab, bA);
  hipLaunchKernelGGL(ln_rows_kernel, dim3(Mtok), dim3(256), 0, stream, bA, bA, lnkv_g, lnkv_b, 0, scale);
  hipLaunchKernelGGL(gemm_kernel, dim3(8, Mtok/64), dim3(256), 0, stream, bA, Wk, bK, Mtok, 512, 512,
                     (const float*)nullptr, (const float*)nullptr, 0, 0);
  hipLaunchKernelGGL(gemm_kernel, dim3(8, Mtok/64), dim3(256), 0, stream, bA, Wv, bV, Mtok, 512, 512,
                     (const float*)nullptr, (const float*)nullptr, 0, 0);
  hipLaunchKernelGGL(gemm_kernel, dim3(8, 1), dim3(256), 0, stream, qc_ln, Wq, qc_proj, 16, 512, 512,
                     (const float*)nullptr, (const float*)nullptr, 0, 0);

  // ---- phase 1: attention + Wo + FFN ----
  hipLaunchKernelGGL(attn1_kernel, dim3(M2tok), dim3(128), 0, stream, bK, bV, qc_proj, bA);
  hipLaunchKernelGGL(gemm_kernel, dim3(8, Mtok/64), dim3(256), 0, stream, bA, Wo, bY, Mtok, 512, 512,
                     (const float*)nullptr, qc_ln, 1, 0);
  hipLaunchKernelGGL(ln_rows_kernel, dim3(Mtok), dim3(256), 0, stream, bY, bA, ffn_g, ffn_b, 0, scale);
  for (int p = 0; p < 8; p++){
    size_t mo = (size_t)p*4096;
    hipLaunchKernelGGL(gemm_kernel, dim3(16, 4096/64), dim3(256), 0, stream, bA + mo*512, W1, bH, 4096, 1024, 512,
                       b1, (const float*)nullptr, 0, 1);
    hipLaunchKernelGGL(gemm_kernel, dim3(8, 4096/64), dim3(256), 0, stream, bH, W2, bY + mo*512, 4096, 512, 1024,
                       b2, bY + mo*512, 2, 0);
  }

  // ---- phase 1: residual -> tanh LN -> Wd -> VQ -> Wu -> z_hat ----
  hipLaunchKernelGGL(resid_kernel, tgrid, tpb32, 0, stream, zt, bY, bA);
  hipLaunchKernelGGL(ln_rows_kernel, dim3(Mtok), dim3(256), 0, stream, bA, bA, tn_g, tn_b, 1, scale);
  hipLaunchKernelGGL(gemm_kernel, dim3(2, Mtok/64), dim3(256), 0, stream, bA, WdT, bX, Mtok, 96, 512,
                     bd, (const float*)nullptr, 0, 0);
  hipLaunchKernelGGL(vq_kernel, dim3(Mtok/64), dim3(256), 0, stream, bX, books, hbuf);
  hipLaunchKernelGGL(gemm_kernel, dim3(8, Mtok/64), dim3(256), 0, stream, bX, WuT, bA, Mtok, 512, 96,
                     bu, bY, 2, 0);
  hipLaunchKernelGGL(tout_kernel, tgrid, tpb32, 0, stream, bA, out);

  // ---- phase 2: token 0 of each chunk with true carries ----
  hipLaunchKernelGGL(q2_kernel, dim3(M2tok), dim3(256), 0, stream, out, p2q, lnq_g, lnq_b);
  hipLaunchKernelGGL(gemm_kernel, dim3(8, M2tok/64), dim3(256), 0, stream, p2q, Wq, p2Qp, M2tok, 512, 512,
                     (const float*)nullptr, (const float*)nullptr, 0, 0);
  hipLaunchKernelGGL(attn2_kernel, dim3(M2tok), dim3(64), 0, stream, bK, bV, p2Qp, p2ctx);
  hipLaunchKernelGGL(gemm_kernel, dim3(8, M2tok/64), dim3(256), 0, stream, p2ctx, Wo, p2y, M2tok, 512, 512,
                     (const float*)nullptr, p2q, 2, 0);
  hipLaunchKernelGGL(ln_rows_kernel, dim3(M2tok), dim3(256), 0, stream, p2y, p2lny, ffn_g, ffn_b, 0, scale);
  hipLaunchKernelGGL(gemm_kernel, dim3(16, M2tok/64), dim3(256), 0, stream, p2lny, W1, p2h, M2tok, 1024, 512,
                     b1, (const float*)nullptr, 0, 1);
  hipLaunchKernelGGL(gemm_kernel, dim3(8, M2tok/64), dim3(256), 0, stream, p2h, W2, p2y, M2tok, 512, 1024,
                     b2, p2y, 2, 0);
  hipLaunchKernelGGL(r2_kernel, dim3(M2tok), dim3(256), 0, stream, zt, p2y, p2r);
  hipLaunchKernelGGL(ln_rows_kernel, dim3(M2tok), dim3(256), 0, stream, p2r, p2r, tn_g, tn_b, 1, scale);
  hipLaunchKernelGGL(gemm_kernel, dim3(2, M2tok/64), dim3(256), 0, stream, p2r, WdT, p2x, M2tok, 96, 512,
                     bd, (const float*)nullptr, 0, 0);
  hipLaunchKernelGGL(vq_kernel, dim3(M2tok/64), dim3(256), 0, stream, p2x, books, hbuf);
  hipLaunchKernelGGL(gemm_kernel, dim3(8, M2tok/64), dim3(256), 0, stream, p2x, WuT, p2z, M2tok, 512, 96,
                     bu, p2y, 2, 0);
  hipLaunchKernelGGL(scatter2_kernel, dim3(M2tok), dim3(256), 0, stream, p2z, out);

  (void)in_sizes; (void)n_in; (void)out_size; (void)ws_size;
}

// Round 3
// 6446.853 us; speedup vs baseline: 1.0972x; 1.0972x over previous
//
#include <hip/hip_runtime.h>
#include <math.h>

#define Bsz 8
#define Cdim 512
#define Tdim 4096
#define NHq 8
#define CD 96
#define NB 8
#define NE 1024
#define NCHq 256
#define Mtok (Bsz*Tdim)     // 32768
#define M2tok (Bsz*NCHq)    // 2048

// ---------------- pe + constant query rows ----------------
__global__ __launch_bounds__(256) void pe_qc_kernel(float* pe_tab, float* qc_ln,
        const float* __restrict__ lnq_g, const float* __restrict__ lnq_b){
  int t = blockIdx.x;           // 0..15
  int tid = threadIdx.x;
  __shared__ float red[256];
  double f = -log(10000.0) / (double)Cdim;
  float v[2];
  #pragma unroll
  for (int u = 0; u < 2; ++u){
    int c = tid + u*256;
    int ce = c & ~1;
    double ang = (double)t * exp(f * (double)ce);
    v[u] = (float)((c & 1) ? cos(ang) : sin(ang));
    pe_tab[t*Cdim + c] = v[u];
  }
  red[tid] = v[0] + v[1]; __syncthreads();
  for (int s = 128; s > 0; s >>= 1){ if (tid < s) red[tid] += red[tid+s]; __syncthreads(); }
  float mean = red[0] * (1.f/512.f); __syncthreads();
  float d0 = v[0]-mean, d1 = v[1]-mean;
  red[tid] = d0*d0 + d1*d1; __syncthreads();
  for (int s = 128; s > 0; s >>= 1){ if (tid < s) red[tid] += red[tid+s]; __syncthreads(); }
  float rstd = 1.0f/sqrtf(red[0]*(1.f/512.f) + 1e-5f);
  qc_ln[t*Cdim + tid]       = d0*rstd*lnq_g[tid]     + lnq_b[tid];
  qc_ln[t*Cdim + tid + 256] = d1*rstd*lnq_g[tid+256] + lnq_b[tid+256];
}

// ---------------- generic row LayerNorm (rows of 512) ----------------
// mode 0: dst = norm*g+b ; mode 1: dst = tanh(norm*g+b)*clip(scale)
__global__ __launch_bounds__(256) void ln_rows_kernel(const float* __restrict__ src, float* __restrict__ dst,
        const float* __restrict__ g, const float* __restrict__ bia, int mode, const float* __restrict__ scale_ptr){
  int row = blockIdx.x; int tid = threadIdx.x;
  const float* sr = src + (size_t)row*Cdim;
  float v0 = sr[tid], v1 = sr[tid+256];
  __shared__ float red[256];
  red[tid] = v0+v1; __syncthreads();
  for (int s = 128; s > 0; s >>= 1){ if (tid < s) red[tid] += red[tid+s]; __syncthreads(); }
  float mean = red[0]*(1.f/512.f); __syncthreads();
  float d0 = v0-mean, d1 = v1-mean;
  red[tid] = d0*d0 + d1*d1; __syncthreads();
  for (int s = 128; s > 0; s >>= 1){ if (tid < s) red[tid] += red[tid+s]; __syncthreads(); }
  float rstd = 1.0f/sqrtf(red[0]*(1.f/512.f) + 1e-5f);
  float h0 = d0*rstd*g[tid]     + bia[tid];
  float h1 = d1*rstd*g[tid+256] + bia[tid+256];
  if (mode == 1){
    float sc = *scale_ptr; sc = fminf(fmaxf(sc, 0.005f), 0.5f);
    h0 = tanhf(h0)*sc; h1 = tanhf(h1)*sc;
  }
  float* dr = dst + (size_t)row*Cdim;
  dr[tid] = h0; dr[tid+256] = h1;
}

// ---------------- transposes [B,C,T] <-> token rows [B*T, C] ----------------
__global__ void tin_kernel(const float* __restrict__ qa, const float* __restrict__ pe_tab, float* __restrict__ rows){
  __shared__ float tile[32][33];
  int b = blockIdx.z, c0 = blockIdx.y*32, t0 = blockIdx.x*32;
  int tx = threadIdx.x, ty = threadIdx.y;
  int t = t0 + tx;
  #pragma unroll
  for (int j = 0; j < 4; j++){
    int c = c0 + ty + j*8;
    tile[ty+j*8][tx] = qa[((size_t)(b*Cdim + c))*Tdim + t] + pe_tab[(t & 15)*Cdim + c];
  }
  __syncthreads();
  #pragma unroll
  for (int j = 0; j < 4; j++){
    int tt = t0 + ty + j*8;
    rows[((size_t)(b*Tdim + tt))*Cdim + c0 + tx] = tile[tx][ty+j*8];
  }
}

__global__ void resid_kernel(const float* __restrict__ zt, const float* __restrict__ zp_rows, float* __restrict__ rows){
  __shared__ float tile[32][33];
  int b = blockIdx.z, c0 = blockIdx.y*32, t0 = blockIdx.x*32;
  int tx = threadIdx.x, ty = threadIdx.y;
  int t = t0 + tx;
  #pragma unroll
  for (int j = 0; j < 4; j++){
    int c = c0 + ty + j*8;
    tile[ty+j*8][tx] = zt[((size_t)(b*Cdim + c))*Tdim + t];
  }
  __syncthreads();
  #pragma unroll
  for (int j = 0; j < 4; j++){
    int tt = t0 + ty + j*8;
    size_t o = ((size_t)(b*Tdim + tt))*Cdim + c0 + tx;
    rows[o] = tile[tx][ty+j*8] - zp_rows[o];
  }
}

__global__ void tout_kernel(const float* __restrict__ rows, float* __restrict__ out){
  __shared__ float tile[32][33];
  int b = blockIdx.z, c0 = blockIdx.y*32, t0 = blockIdx.x*32;
  int tx = threadIdx.x, ty = threadIdx.y;
  #pragma unroll
  for (int j = 0; j < 4; j++){
    int tt = t0 + ty + j*8;
    tile[ty+j*8][tx] = rows[((size_t)(b*Tdim + tt))*Cdim + c0 + tx];
  }
  __syncthreads();
  #pragma unroll
  for (int j = 0; j < 4; j++){
    int c = c0 + ty + j*8;
    out[((size_t)(b*Cdim + c))*Tdim + t0 + tx] = tile[tx][ty+j*8];
  }
}

// ---------------- weight transposes ----------------
__global__ void twd_kernel(const float* __restrict__ Wd, float* __restrict__ WdT){ // Wd[96][512] -> WdT[512][96]
  int i = blockIdx.x*256 + threadIdx.x; if (i >= 96*512) return;
  int kq = i / 96, n = i % 96;
  WdT[i] = Wd[(size_t)n*512 + kq];
}
__global__ void twu_kernel(const float* __restrict__ Wu, float* __restrict__ WuT){ // Wu[512][96] -> WuT[96][512]
  int i = blockIdx.x*256 + threadIdx.x; if (i >= 96*512) return;
  int d = i / 512, c = i % 512;
  WuT[i] = Wu[(size_t)c*96 + d];
}

// ---------------- 0.5*||e||^2 per codebook entry ----------------
__global__ void hb_kernel(const float* __restrict__ books, float* __restrict__ hb){
  int j = blockIdx.x*256 + threadIdx.x;
  if (j >= NB*NE) return;
  const float* e = books + (size_t)j*CD;
  float s = 0.f;
  #pragma unroll
  for (int d = 0; d < CD; d++) s = fmaf(e[d], e[d], s);
  hb[j] = 0.5f*s;
}

// ---------------- generic tiled fp32 GEMM (64x64 tile): odd shapes only ----------------
// addmode: 0 none, 1 addbuf[(m&15)*N+n], 2 addbuf[m*N+n]
__global__ __launch_bounds__(256) void gemm_kernel(const float* __restrict__ A, const float* __restrict__ Bm,
        float* __restrict__ Cm, int M, int N, int K,
        const float* __restrict__ bias, const float* __restrict__ addbuf, int addmode, int act){
  __shared__ float As[16][65];
  __shared__ float Bs[16][64];
  int l = threadIdx.x;
  int tx = l & 15, ty = l >> 4;
  int m0 = blockIdx.y*64, n0 = blockIdx.x*64;
  int ai = l >> 2, ak = (l & 3)*4;
  int bk = l >> 4, bj = (l & 15)*4;
  float acc[4][4] = {{0.f}};
  bool nfull = (n0 + 64 <= N);
  for (int k0 = 0; k0 < K; k0 += 16){
    float4 av = make_float4(0.f, 0.f, 0.f, 0.f);
    if (m0 + ai < M) av = *(const float4*)(A + (size_t)(m0+ai)*K + k0 + ak);
    As[ak][ai] = av.x; As[ak+1][ai] = av.y; As[ak+2][ai] = av.z; As[ak+3][ai] = av.w;
    if (nfull){
      *(float4*)(&Bs[bk][bj]) = *(const float4*)(Bm + (size_t)(k0+bk)*N + n0 + bj);
    } else {
      #pragma unroll
      for (int u = 0; u < 4; u++){
        int n = n0 + bj + u;
        Bs[bk][bj+u] = (n < N) ? Bm[(size_t)(k0+bk)*N + n] : 0.f;
      }
    }
    __syncthreads();
    #pragma unroll
    for (int kk = 0; kk < 16; kk++){
      float a0 = As[kk][ty*4], a1 = As[kk][ty*4+1], a2 = As[kk][ty*4+2], a3 = As[kk][ty*4+3];
      float b0 = Bs[kk][tx*4], b1 = Bs[kk][tx*4+1], b2 = Bs[kk][tx*4+2], b3 = Bs[kk][tx*4+3];
      acc[0][0] = fmaf(a0,b0,acc[0][0]); acc[0][1] = fmaf(a0,b1,acc[0][1]);
      acc[0][2] = fmaf(a0,b2,acc[0][2]); acc[0][3] = fmaf(a0,b3,acc[0][3]);
      acc[1][0] = fmaf(a1,b0,acc[1][0]); acc[1][1] = fmaf(a1,b1,acc[1][1]);
      acc[1][2] = fmaf(a1,b2,acc[1][2]); acc[1][3] = fmaf(a1,b3,acc[1][3]);
      acc[2][0] = fmaf(a2,b0,acc[2][0]); acc[2][1] = fmaf(a2,b1,acc[2][1]);
      acc[2][2] = fmaf(a2,b2,acc[2][2]); acc[2][3] = fmaf(a2,b3,acc[2][3]);
      acc[3][0] = fmaf(a3,b0,acc[3][0]); acc[3][1] = fmaf(a3,b1,acc[3][1]);
      acc[3][2] = fmaf(a3,b2,acc[3][2]); acc[3][3] = fmaf(a3,b3,acc[3][3]);
    }
    __syncthreads();
  }
  #pragma unroll
  for (int r = 0; r < 4; r++){
    int m = m0 + ty*4 + r; if (m >= M) continue;
    #pragma unroll
    for (int c = 0; c < 4; c++){
      int n = n0 + tx*4 + c; if (n >= N) continue;
      float v = acc[r][c];
      if (bias) v += bias[n];
      if (act == 1) v = 0.5f*v*(1.0f + erff(v*0.7071067811865475f));
      if (addmode == 1) v += addbuf[(size_t)(m & 15)*N + n];
      else if (addmode == 2) v += addbuf[(size_t)m*N + n];
      Cm[(size_t)m*N + n] = v;
    }
  }
}

// ---------------- fast fp32 GEMM: 128x128 tile, 8x8 acc/thread ----------------
// requires M%128==0, N%128==0, K%16==0
__global__ __launch_bounds__(256) void fgemm_kernel(const float* __restrict__ A, const float* __restrict__ Bm,
        float* __restrict__ Cm, int M, int N, int K,
        const float* __restrict__ bias, const float* __restrict__ addbuf, int addmode, int act){
  __shared__ float As[16][128];
  __shared__ float Bs[16][128];
  int l = threadIdx.x;
  int tx = l & 15, ty = l >> 4;          // 16x16 thread grid
  int m0 = blockIdx.y*128, n0 = blockIdx.x*128;
  int ar = l >> 1, ac = (l & 1) * 8;     // A staging: 128 rows x 16 cols, 2 thr/row
  int br = l >> 4, bc = (l & 15) * 8;    // B staging: 16 rows x 128 cols
  float acc[8][8] = {{0.f}};
  const float* Aptr = A + (size_t)(m0 + ar)*K + ac;
  const float* Bptr = Bm + (size_t)br*N + n0 + bc;
  for (int k0 = 0; k0 < K; k0 += 16){
    float4 a0 = *(const float4*)(Aptr + k0);
    float4 a1 = *(const float4*)(Aptr + k0 + 4);
    float4 bv0 = *(const float4*)(Bptr + (size_t)k0*N);
    float4 bv1 = *(const float4*)(Bptr + (size_t)k0*N + 4);
    As[ac+0][ar]=a0.x; As[ac+1][ar]=a0.y; As[ac+2][ar]=a0.z; As[ac+3][ar]=a0.w;
    As[ac+4][ar]=a1.x; As[ac+5][ar]=a1.y; As[ac+6][ar]=a1.z; As[ac+7][ar]=a1.w;
    *(float4*)(&Bs[br][bc])   = bv0;
    *(float4*)(&Bs[br][bc+4]) = bv1;
    __syncthreads();
    #pragma unroll
    for (int kk = 0; kk < 16; kk++){
      float av[8], bw[8];
      *(float4*)(av)   = *(const float4*)(&As[kk][ty*4]);
      *(float4*)(av+4) = *(const float4*)(&As[kk][64 + ty*4]);
      *(float4*)(bw)   = *(const float4*)(&Bs[kk][tx*4]);
      *(float4*)(bw+4) = *(const float4*)(&Bs[kk][64 + tx*4]);
      #pragma unroll
      for (int i = 0; i < 8; i++)
        #pragma unroll
        for (int j = 0; j < 8; j++)
          acc[i][j] = fmaf(av[i], bw[j], acc[i][j]);
    }
    __syncthreads();
  }
  #pragma unroll
  for (int i = 0; i < 8; i++){
    int m = m0 + ((i < 4) ? (ty*4 + i) : (64 + ty*4 + i - 4));
    #pragma unroll
    for (int jh = 0; jh < 2; jh++){
      int nb = n0 + jh*64 + tx*4;
      float v[4];
      #pragma unroll
      for (int j = 0; j < 4; j++){
        float u = acc[i][jh*4 + j];
        int n = nb + j;
        if (bias) u += bias[n];
        if (act == 1) u = 0.5f*u*(1.0f + erff(u*0.7071067811865475f));
        if (addmode == 1) u += addbuf[(size_t)(m & 15)*N + n];
        else if (addmode == 2) u += addbuf[(size_t)m*N + n];
        v[j] = u;
      }
      *(float4*)(Cm + (size_t)m*N + nb) = *(float4*)v;
    }
  }
}

// ---------------- attention, phase 1: 16 const queries x 16 keys per (b,chunk) ----------------
__global__ __launch_bounds__(128) void attn1_kernel(const float* __restrict__ Kb, const float* __restrict__ Vb,
        const float* __restrict__ Qp, float* __restrict__ ctxb){
  int idx = blockIdx.x;                 // b*256 + ch
  int b = idx >> 8, ch = idx & 255;
  size_t m0 = (size_t)b*Tdim + ch*16;
  int t = threadIdx.x >> 3, h = threadIdx.x & 7;
  const float* q = Qp + t*Cdim + h*64;
  float qr[64];
  #pragma unroll
  for (int d = 0; d < 64; d += 4){ float4 f = *(const float4*)(q+d); qr[d]=f.x; qr[d+1]=f.y; qr[d+2]=f.z; qr[d+3]=f.w; }
  float s[16];
  #pragma unroll
  for (int k = 0; k < 16; k++){
    const float* kr = Kb + (m0+k)*Cdim + h*64;
    float acc = 0.f;
    #pragma unroll
    for (int d = 0; d < 64; d += 4){
      float4 f = *(const float4*)(kr+d);
      acc = fmaf(qr[d],f.x,acc); acc = fmaf(qr[d+1],f.y,acc);
      acc = fmaf(qr[d+2],f.z,acc); acc = fmaf(qr[d+3],f.w,acc);
    }
    s[k] = acc * 0.125f;
  }
  float mx = s[0];
  #pragma unroll
  for (int k = 1; k < 16; k++) mx = fmaxf(mx, s[k]);
  float sum = 0.f;
  #pragma unroll
  for (int k = 0; k < 16; k++){ s[k] = expf(s[k]-mx); sum += s[k]; }
  float inv = 1.0f/sum;
  float ctx[64];
  #pragma unroll
  for (int d = 0; d < 64; d++) ctx[d] = 0.f;
  #pragma unroll
  for (int k = 0; k < 16; k++){
    float p = s[k]*inv;
    const float* vr = Vb + (m0+k)*Cdim + h*64;
    #pragma unroll
    for (int d = 0; d < 64; d += 4){
      float4 f = *(const float4*)(vr+d);
      ctx[d]=fmaf(p,f.x,ctx[d]); ctx[d+1]=fmaf(p,f.y,ctx[d+1]);
      ctx[d+2]=fmaf(p,f.z,ctx[d+2]); ctx[d+3]=fmaf(p,f.w,ctx[d+3]);
    }
  }
  float* o = ctxb + (m0+t)*Cdim + h*64;
  #pragma unroll
  for (int d = 0; d < 64; d += 4){
    float4 f; f.x=ctx[d]; f.y=ctx[d+1]; f.z=ctx[d+2]; f.w=ctx[d+3];
    *(float4*)(o+d) = f;
  }
}

// ---------------- attention, phase 2: 1 query (token 0) per (b,chunk) ----------------
__global__ __launch_bounds__(64) void attn2_kernel(const float* __restrict__ Kb, const float* __restrict__ Vb,
        const float* __restrict__ Qp, float* __restrict__ ctxb){
  int m2 = blockIdx.x;                 // b*256 + ch
  int b = m2 >> 8, ch = m2 & 255;
  size_t m0 = (size_t)b*Tdim + ch*16;
  int h = threadIdx.x;
  if (h >= 8) return;
  const float* q = Qp + (size_t)m2*Cdim + h*64;
  float qr[64];
  #pragma unroll
  for (int d = 0; d < 64; d += 4){ float4 f = *(const float4*)(q+d); qr[d]=f.x; qr[d+1]=f.y; qr[d+2]=f.z; qr[d+3]=f.w; }
  float s[16];
  #pragma unroll
  for (int k = 0; k < 16; k++){
    const float* kr = Kb + (m0+k)*Cdim + h*64;
    float acc = 0.f;
    #pragma unroll
    for (int d = 0; d < 64; d += 4){
      float4 f = *(const float4*)(kr+d);
      acc = fmaf(qr[d],f.x,acc); acc = fmaf(qr[d+1],f.y,acc);
      acc = fmaf(qr[d+2],f.z,acc); acc = fmaf(qr[d+3],f.w,acc);
    }
    s[k] = acc * 0.125f;
  }
  float mx = s[0];
  #pragma unroll
  for (int k = 1; k < 16; k++) mx = fmaxf(mx, s[k]);
  float sum = 0.f;
  #pragma unroll
  for (int k = 0; k < 16; k++){ s[k] = expf(s[k]-mx); sum += s[k]; }
  float inv = 1.0f/sum;
  float ctx[64];
  #pragma unroll
  for (int d = 0; d < 64; d++) ctx[d] = 0.f;
  #pragma unroll
  for (int k = 0; k < 16; k++){
    float p = s[k]*inv;
    const float* vr = Vb + (m0+k)*Cdim + h*64;
    #pragma unroll
    for (int d = 0; d < 64; d += 4){
      float4 f = *(const float4*)(vr+d);
      ctx[d]=fmaf(p,f.x,ctx[d]); ctx[d+1]=fmaf(p,f.y,ctx[d+1]);
      ctx[d+2]=fmaf(p,f.z,ctx[d+2]); ctx[d+3]=fmaf(p,f.w,ctx[d+3]);
    }
  }
  float* o = ctxb + (size_t)m2*Cdim + h*64;
  #pragma unroll
  for (int d = 0; d < 64; d += 4){
    float4 f; f.x=ctx[d]; f.y=ctx[d+1]; f.z=ctx[d+2]; f.w=ctx[d+3];
    *(float4*)(o+d) = f;
  }
}

// ---------------- phase 2: build token-0 query rows (carry + pe[:,0], LN) ----------------
__global__ __launch_bounds__(256) void q2_kernel(const float* __restrict__ dout, float* __restrict__ p2q,
        const float* __restrict__ g, const float* __restrict__ bia){
  int m2 = blockIdx.x; int tid = threadIdx.x;
  int b = m2 >> 8, ch = m2 & 255;
  int tprev = ch*16 - 1;
  float v0, v1;
  {
    int c = tid;
    float carry = (ch == 0) ? 0.f : dout[((size_t)(b*Cdim + c))*Tdim + tprev];
    v0 = carry + ((c & 1) ? 1.f : 0.f);     // pe[c,0] = c even ? sin(0)=0 : cos(0)=1
  }
  {
    int c = tid + 256;
    float carry = (ch == 0) ? 0.f : dout[((size_t)(b*Cdim + c))*Tdim + tprev];
    v1 = carry + ((c & 1) ? 1.f : 0.f);
  }
  __shared__ float red[256];
  red[tid] = v0+v1; __syncthreads();
  for (int s = 128; s > 0; s >>= 1){ if (tid < s) red[tid] += red[tid+s]; __syncthreads(); }
  float mean = red[0]*(1.f/512.f); __syncthreads();
  float d0 = v0-mean, d1 = v1-mean;
  red[tid] = d0*d0 + d1*d1; __syncthreads();
  for (int s = 128; s > 0; s >>= 1){ if (tid < s) red[tid] += red[tid+s]; __syncthreads(); }
  float rstd = 1.0f/sqrtf(red[0]*(1.f/512.f) + 1e-5f);
  p2q[(size_t)m2*Cdim + tid]       = d0*rstd*g[tid]     + bia[tid];
  p2q[(size_t)m2*Cdim + tid + 256] = d1*rstd*g[tid+256] + bia[tid+256];
}

// ---------------- phase 2: r = zt[:, :, t0] - z_pred0 ----------------
__global__ __launch_bounds__(256) void r2_kernel(const float* __restrict__ zt, const float* __restrict__ zp,
        float* __restrict__ out){
  int m2 = blockIdx.x; int tid = threadIdx.x;
  int b = m2 >> 8, ch = m2 & 255; int t0 = ch*16;
  #pragma unroll
  for (int u = 0; u < 2; u++){
    int c = tid + u*256;
    out[(size_t)m2*Cdim + c] = zt[((size_t)(b*Cdim + c))*Tdim + t0] - zp[(size_t)m2*Cdim + c];
  }
}

// ---------------- phase 2: scatter z_hat token-0 columns into d_out ----------------
__global__ __launch_bounds__(256) void scatter2_kernel(const float* __restrict__ z, float* __restrict__ dout){
  int m2 = blockIdx.x; int tid = threadIdx.x;
  int b = m2 >> 8, ch = m2 & 255; int t0 = ch*16;
  #pragma unroll
  for (int u = 0; u < 2; u++){
    int c = tid + u*256;
    dout[((size_t)(b*Cdim + c))*Tdim + t0] = z[(size_t)m2*Cdim + c];
  }
}

// ---------------- residual VQ: 8 codebooks, straight-through == q_sum = x - residual_8 ----------------
// NW waves per block, 64 tokens/block (token per lane); wave w scans candidates
// [w*(1024/NW), (w+1)*(1024/NW)), 4 candidates per iteration (4 indep FMA chains).
template<int NW>
__global__ __launch_bounds__(64*NW) void vq_kernel(float* __restrict__ x, const float* __restrict__ books,
        const float* __restrict__ hb){
  const int RNG = NE / NW;
  int lane = threadIdx.x & 63;
  int wv = threadIdx.x >> 6;
  size_t tok = (size_t)blockIdx.x*64 + lane;
  float res[96];
  #pragma unroll
  for (int d = 0; d < 96; d += 4){
    float4 f = *(const float4*)(x + tok*CD + d);
    res[d]=f.x; res[d+1]=f.y; res[d+2]=f.z; res[d+3]=f.w;
  }
  __shared__ float s_best[NW][64];
  __shared__ int   s_idx[NW][64];
  __shared__ int   s_sel[64];
  for (int k = 0; k < NB; k++){
    const float* bk = books + (size_t)k*NE*CD;
    const float* hk = hb + k*NE;
    float best = -3.0e38f; int bidx = 0;
    int cbase = __builtin_amdgcn_readfirstlane(wv*RNG);
    for (int cc = 0; cc < RNG; cc += 4){
      int c0 = cbase + cc;
      const float* e0 = bk + (size_t)c0*CD;
      float a0 = -hk[c0], a1 = -hk[c0+1], a2 = -hk[c0+2], a3 = -hk[c0+3];
      #pragma unroll
      for (int d = 0; d < 96; d++){
        float r = res[d];
        a0 = fmaf(r, e0[d],       a0);
        a1 = fmaf(r, e0[96+d],    a1);
        a2 = fmaf(r, e0[192+d],   a2);
        a3 = fmaf(r, e0[288+d],   a3);
      }
      if (a0 > best){ best = a0; bidx = c0; }
      if (a1 > best){ best = a1; bidx = c0 + 1; }
      if (a2 > best){ best = a2; bidx = c0 + 2; }
      if (a3 > best){ best = a3; bidx = c0 + 3; }
    }
    s_best[wv][lane] = best; s_idx[wv][lane] = bidx;
    __syncthreads();
    if (wv == 0){
      float bb = s_best[0][lane]; int bi = s_idx[0][lane];
      #pragma unroll
      for (int w = 1; w < NW; w++){
        float b2 = s_best[w][lane]; int i2 = s_idx[w][lane];
        if (b2 > bb){ bb = b2; bi = i2; }      // ranges ascending -> first-max tie rule
      }
      s_sel[lane] = bi;
    }
    __syncthreads();
    int sel = s_sel[lane];
    const float* ev = bk + (size_t)sel*CD;
    #pragma unroll
    for (int d = 0; d < 96; d += 4){
      float4 f = *(const float4*)(ev + d);
      res[d]-=f.x; res[d+1]-=f.y; res[d+2]-=f.z; res[d+3]-=f.w;
    }
    // no barrier needed: each wave re-reads s_sel only after the next barrier pair
  }
  if (wv == 0){
    #pragma unroll
    for (int d = 0; d < 96; d += 4){
      float4 xo = *(const float4*)(x + tok*CD + d);
      float4 q;
      q.x = xo.x - res[d]; q.y = xo.y - res[d+1]; q.z = xo.z - res[d+2]; q.w = xo.w - res[d+3];
      *(float4*)(x + tok*CD + d) = q;
    }
  }
}

// ---------------- host ----------------
extern "C" void kernel_launch(void* const* d_in, const int* in_sizes, int n_in,
                              void* d_out, int out_size, void* d_ws, size_t ws_size,
                              hipStream_t stream) {
  const float* qa    = (const float*)d_in[0];
  const float* zt    = (const float*)d_in[1];
  const float* lnq_g = (const float*)d_in[2];
  const float* lnq_b = (const float*)d_in[3];
  const float* lnkv_g= (const float*)d_in[4];
  const float* lnkv_b= (const float*)d_in[5];
  const float* Wq    = (const float*)d_in[6];
  const float* Wk    = (const float*)d_in[7];
  const float* Wv    = (const float*)d_in[8];
  const float* Wo    = (const float*)d_in[9];
  const float* ffn_g = (const float*)d_in[10];
  const float* ffn_b = (const float*)d_in[11];
  const float* W1    = (const float*)d_in[12];
  const float* b1    = (const float*)d_in[13];
  const float* W2    = (const float*)d_in[14];
  const float* b2    = (const float*)d_in[15];
  const float* tn_g  = (const float*)d_in[16];
  const float* tn_b  = (const float*)d_in[17];
  const float* scale = (const float*)d_in[18];
  const float* Wd    = (const float*)d_in[19];
  const float* bd    = (const float*)d_in[20];
  const float* Wu    = (const float*)d_in[21];
  const float* bu    = (const float*)d_in[22];
  const float* books = (const float*)d_in[23];
  float* out = (float*)d_out;

  // ---- workspace layout (total ~208.5 MiB) ----
  float* ws = (float*)d_ws;
  size_t off = 0;
  float* pe_tab  = ws + off; off += 16*512;
  float* qc_ln   = ws + off; off += 16*512;
  float* qc_proj = ws + off; off += 16*512;
  float* WdT     = ws + off; off += 512*96;
  float* WuT     = ws + off; off += 96*512;
  float* hbuf    = ws + off; off += 8*1024;
  float* bA      = ws + off; off += (size_t)Mtok*512;   // kv rows -> ctx -> lny -> rn -> zhat rows -> phase2 scratch
  float* bK      = ws + off; off += (size_t)Mtok*512;
  float* bV      = ws + off; off += (size_t)Mtok*512;
  float* bH      = ws + off; off += (size_t)4096*1024;  // FFN hidden tile; also hosts bX
  float* bX      = bH;                                  // Mtok*96 = 12.6MB <= 16.8MB, used after FFN done
  // y / z_pred rows [Mtok,512] live in d_out (same element count); dead before tout overwrites d_out
  float* bY      = out;

  // phase-2 scratch carved inside bA (only used after tout consumes bA)
  float* p2q   = bA;
  float* p2Qp  = bA + 1048576;
  float* p2ctx = bA + 2*1048576;
  float* p2y   = bA + 3*1048576;
  float* p2lny = bA + 4*1048576;
  float* p2h   = bA + 5*1048576;          // 2048*1024
  float* p2r   = bA + 7*1048576;
  float* p2x   = bA + 8*1048576;          // 2048*96
  float* p2z   = bA + 8*1048576 + 196608;

  dim3 tpb32(32, 8);
  dim3 tgrid(Tdim/32, Cdim/32, Bsz);

  // ---- prep ----
  hipLaunchKernelGGL(pe_qc_kernel, dim3(16), dim3(256), 0, stream, pe_tab, qc_ln, lnq_g, lnq_b);
  hipLaunchKernelGGL(twd_kernel, dim3((96*512+255)/256), dim3(256), 0, stream, Wd, WdT);
  hipLaunchKernelGGL(twu_kernel, dim3((96*512+255)/256), dim3(256), 0, stream, Wu, WuT);
  hipLaunchKernelGGL(hb_kernel, dim3((NB*NE+255)/256), dim3(256), 0, stream, books, hbuf);

  // ---- phase 1: kv path ----
  hipLaunchKernelGGL(tin_kernel, tgrid, tpb32, 0, stream, qa, pe_tab, bA);
  hipLaunchKernelGGL(ln_rows_kernel, dim3(Mtok), dim3(256), 0, stream, bA, bA, lnkv_g, lnkv_b, 0, scale);
  hipLaunchKernelGGL(fgemm_kernel, dim3(4, Mtok/128), dim3(256), 0, stream, bA, Wk, bK, Mtok, 512, 512,
                     (const float*)nullptr, (const float*)nullptr, 0, 0);
  hipLaunchKernelGGL(fgemm_kernel, dim3(4, Mtok/128), dim3(256), 0, stream, bA, Wv, bV, Mtok, 512, 512,
                     (const float*)nullptr, (const float*)nullptr, 0, 0);
  hipLaunchKernelGGL(gemm_kernel, dim3(8, 1), dim3(256), 0, stream, qc_ln, Wq, qc_proj, 16, 512, 512,
                     (const float*)nullptr, (const float*)nullptr, 0, 0);

  // ---- phase 1: attention + Wo + FFN ----
  hipLaunchKernelGGL(attn1_kernel, dim3(M2tok), dim3(128), 0, stream, bK, bV, qc_proj, bA);
  hipLaunchKernelGGL(fgemm_kernel, dim3(4, Mtok/128), dim3(256), 0, stream, bA, Wo, bY, Mtok, 512, 512,
                     (const float*)nullptr, qc_ln, 1, 0);
  hipLaunchKernelGGL(ln_rows_kernel, dim3(Mtok), dim3(256), 0, stream, bY, bA, ffn_g, ffn_b, 0, scale);
  for (int p = 0; p < 8; p++){
    size_t mo = (size_t)p*4096;
    hipLaunchKernelGGL(fgemm_kernel, dim3(8, 4096/128), dim3(256), 0, stream, bA + mo*512, W1, bH, 4096, 1024, 512,
                       b1, (const float*)nullptr, 0, 1);
    hipLaunchKernelGGL(fgemm_kernel, dim3(4, 4096/128), dim3(256), 0, stream, bH, W2, bY + mo*512, 4096, 512, 1024,
                       b2, bY + mo*512, 2, 0);
  }

  // ---- phase 1: residual -> tanh LN -> Wd -> VQ -> Wu -> z_hat ----
  hipLaunchKernelGGL(resid_kernel, tgrid, tpb32, 0, stream, zt, bY, bA);
  hipLaunchKernelGGL(ln_rows_kernel, dim3(Mtok), dim3(256), 0, stream, bA, bA, tn_g, tn_b, 1, scale);
  hipLaunchKernelGGL(gemm_kernel, dim3(2, Mtok/64), dim3(256), 0, stream, bA, WdT, bX, Mtok, 96, 512,
                     bd, (const float*)nullptr, 0, 0);
  hipLaunchKernelGGL(vq_kernel<8>, dim3(Mtok/64), dim3(512), 0, stream, bX, books, hbuf);
  hipLaunchKernelGGL(fgemm_kernel, dim3(4, Mtok/128), dim3(256), 0, stream, bX, WuT, bA, Mtok, 512, 96,
                     bu, bY, 2, 0);
  hipLaunchKernelGGL(tout_kernel, tgrid, tpb32, 0, stream, bA, out);

  // ---- phase 2: token 0 of each chunk with true carries ----
  hipLaunchKernelGGL(q2_kernel, dim3(M2tok), dim3(256), 0, stream, out, p2q, lnq_g, lnq_b);
  hipLaunchKernelGGL(fgemm_kernel, dim3(4, M2tok/128), dim3(256), 0, stream, p2q, Wq, p2Qp, M2tok, 512, 512,
                     (const float*)nullptr, (const float*)nullptr, 0, 0);
  hipLaunchKernelGGL(attn2_kernel, dim3(M2tok), dim3(64), 0, stream, bK, bV, p2Qp, p2ctx);
  hipLaunchKernelGGL(fgemm_kernel, dim3(4, M2tok/128), dim3(256), 0, stream, p2ctx, Wo, p2y, M2tok, 512, 512,
                     (const float*)nullptr, p2q, 2, 0);
  hipLaunchKernelGGL(ln_rows_kernel, dim3(M2tok), dim3(256), 0, stream, p2y, p2lny, ffn_g, ffn_b, 0, scale);
  hipLaunchKernelGGL(fgemm_kernel, dim3(8, M2tok/128), dim3(256), 0, stream, p2lny, W1, p2h, M2tok, 1024, 512,
                     b1, (const float*)nullptr, 0, 1);
  hipLaunchKernelGGL(fgemm_kernel, dim3(4, M2tok/128), dim3(256), 0, stream, p2h, W2, p2y, M2tok, 512, 1024,
                     b2, p2y, 2, 0);
  hipLaunchKernelGGL(r2_kernel, dim3(M2tok), dim3(256), 0, stream, zt, p2y, p2r);
  hipLaunchKernelGGL(ln_rows_kernel, dim3(M2tok), dim3(256), 0, stream, p2r, p2r, tn_g, tn_b, 1, scale);
  hipLaunchKernelGGL(gemm_kernel, dim3(2, M2tok/64), dim3(256), 0, stream, p2r, WdT, p2x, M2tok, 96, 512,
                     bd, (const float*)nullptr, 0, 0);
  hipLaunchKernelGGL(vq_kernel<16>, dim3(M2tok/64), dim3(1024), 0, stream, p2x, books, hbuf);
  hipLaunchKernelGGL(fgemm_kernel, dim3(4, M2tok/128), dim3(256), 0, stream, p2x, WuT, p2z, M2tok, 512, 96,
                     bu, p2y, 2, 0);
  hipLaunchKernelGGL(scatter2_kernel, dim3(M2tok), dim3(256), 0, stream, p2z, out);

  (void)in_sizes; (void)n_in; (void)out_size; (void)ws_size;
}